// Round 5
// baseline (262.407 us; speedup 1.0000x reference)
//
#include <hip/hip_runtime.h>
#include <math.h>

#define EPSF 0.3f
#define NPB 128      // nodes per bucket
#define SHB 7        // log2(NPB)
#define MAXNB 512    // max buckets
#define CHUNK 16384  // edges per block in hist/binwrite

typedef __attribute__((ext_vector_type(8))) short bf16x8;
typedef __attribute__((ext_vector_type(4))) float f32x4;

// ---------------- bf16 helpers ----------------
__device__ __forceinline__ uint32_t f2bf(float f) {
    uint32_t u = __float_as_uint(f);
    return (u + 0x7fffu + ((u >> 16) & 1u)) >> 16;  // RNE
}
__device__ __forceinline__ uint32_t pack2(float lo, float hi) {
    return f2bf(lo) | (f2bf(hi) << 16);
}
__device__ __forceinline__ float bflo(uint32_t u) { return __uint_as_float(u << 16); }
__device__ __forceinline__ float bfhi(uint32_t u) { return __uint_as_float(u & 0xffff0000u); }

// ---------------- edge dtype probe (int32 vs int64) ----------------
__global__ void k_detect(const int* __restrict__ ei, int* __restrict__ flag) {
    __shared__ int nz;
    if (threadIdx.x == 0) nz = 0;
    __syncthreads();
    for (int t = threadIdx.x; t < 2048; t += 256)
        if (ei[2 * t + 1] != 0) atomicOr(&nz, 1);
    __syncthreads();
    if (threadIdx.x == 0) flag[0] = (nz == 0) ? 1 : 0;  // 1 => int64
}

__device__ __forceinline__ int edge_at(const int* ei, int is64, size_t idx) {
    if (is64) return (int)((const long long*)ei)[idx];
    return ei[idx];
}

// ---------------- bucket histogram ----------------
__global__ __launch_bounds__(256) void k_hist(const int* __restrict__ ei, int E,
                                              const int* __restrict__ flag,
                                              int* __restrict__ hist, int nblk, int NB) {
    __shared__ int lh[MAXNB];
    for (int b = threadIdx.x; b < NB; b += 256) lh[b] = 0;
    __syncthreads();
    int is64 = flag[0];
    int base = blockIdx.x * CHUNK;
    for (int j = threadIdx.x; j < CHUNK; j += 256) {
        int e = base + j;
        if (e < E) {
            int r = edge_at(ei, is64, e);
            atomicAdd(&lh[r >> SHB], 1);
        }
    }
    __syncthreads();
    for (int b = threadIdx.x; b < NB; b += 256)
        hist[(size_t)b * nblk + blockIdx.x] = lh[b];
}

__global__ void k_scanA(int* __restrict__ hist, int nblk, int* __restrict__ btot) {
    int b = blockIdx.x;
    int lane = threadIdx.x;
    int run = 0;
    for (int seg = 0; seg < nblk; seg += 64) {
        int idx = seg + lane;
        int v = (idx < nblk) ? hist[(size_t)b * nblk + idx] : 0;
        int s = v;
        for (int o = 1; o < 64; o <<= 1) {
            int t = __shfl_up(s, o);
            if (lane >= o) s += t;
        }
        if (idx < nblk) hist[(size_t)b * nblk + idx] = run + s - v;
        run += __shfl(s, 63);
    }
    if (lane == 0) btot[b] = run;
}

__global__ void k_scanB(const int* __restrict__ btot, int NB, int* __restrict__ bbase) {
    __shared__ int s[MAXNB];
    int t = threadIdx.x;
    int v = (t < NB) ? btot[t] : 0;
    s[t] = v;
    __syncthreads();
    for (int o = 1; o < MAXNB; o <<= 1) {
        int x = (t >= o) ? s[t - o] : 0;
        __syncthreads();
        s[t] += x;
        __syncthreads();
    }
    if (t < NB) bbase[t] = s[t] - v;
    if (t == MAXNB - 1) bbase[NB] = s[t];
}

// packed ebuf entry: (r & 127) | (c << 7)   (valid for N < 2^25)
__global__ __launch_bounds__(256) void k_binwrite(const int* __restrict__ ei, int E,
                                                  const int* __restrict__ flag,
                                                  const int* __restrict__ hist,
                                                  const int* __restrict__ bbase,
                                                  uint32_t* __restrict__ ebuf,
                                                  int nblk, int NB) {
    __shared__ int lcnt[MAXNB];
    for (int b = threadIdx.x; b < NB; b += 256)
        lcnt[b] = bbase[b] + hist[(size_t)b * nblk + blockIdx.x];
    __syncthreads();
    int is64 = flag[0];
    int base = blockIdx.x * CHUNK;
    for (int j = threadIdx.x; j < CHUNK; j += 256) {
        int e = base + j;
        if (e < E) {
            int r = edge_at(ei, is64, e);
            int c = edge_at(ei, is64, (size_t)E + e);
            int pos = atomicAdd(&lcnt[r >> SHB], 1);
            ebuf[pos] = (uint32_t)(r & (NPB - 1)) | ((uint32_t)c << SHB);
        }
    }
}

__global__ __launch_bounds__(256) void k_csr(const uint32_t* __restrict__ ebuf,
                                             const int* __restrict__ bbase,
                                             int* __restrict__ rp, float* __restrict__ dinv,
                                             int* __restrict__ ecol, int N, int E, int NB) {
    __shared__ int cnt[NPB];
    __shared__ int sc[NPB];
    __shared__ int cur[NPB];
    int b = blockIdx.x;
    int tid = threadIdx.x;
    int p0 = bbase[b], p1 = bbase[b + 1];
    int n0 = b << SHB;
    if (tid < NPB) cnt[tid] = 0;
    __syncthreads();
    for (int p = p0 + tid; p < p1; p += 256)
        atomicAdd(&cnt[ebuf[p] & (NPB - 1)], 1);
    __syncthreads();
    if (tid < NPB) sc[tid] = cnt[tid];
    __syncthreads();
    for (int o = 1; o < NPB; o <<= 1) {
        int v = (tid < NPB && tid >= o) ? sc[tid - o] : 0;
        __syncthreads();
        if (tid < NPB) sc[tid] += v;
        __syncthreads();
    }
    if (tid < NPB) {
        int off = sc[tid] - cnt[tid];
        cur[tid] = off;
        int node = n0 + tid;
        if (node < N) {
            rp[node] = p0 + off;
            int d = cnt[tid];
            dinv[node] = d > 0 ? rsqrtf((float)d) : 0.f;
        }
    }
    if (b == NB - 1 && tid == 0) rp[N] = E;
    __syncthreads();
    for (int p = p0 + tid; p < p1; p += 256) {
        uint32_t v = ebuf[p];
        int pos = p0 + atomicAdd(&cur[v & (NPB - 1)], 1);
        ecol[pos] = (int)(v >> SHB);
    }
}

// ---------------- GEMM1 (MFMA bf16): hb = relu(x @ t1_w^T + b) as bf16 ----------------
__global__ __launch_bounds__(256) void k_gemm1(const float* __restrict__ A,
                                               const float* __restrict__ W,
                                               const float* __restrict__ bias,
                                               uint32_t* __restrict__ hb, int M) {
    __shared__ char As[128 * 128];
    __shared__ char Bs[128 * 128];
    const int tid = threadIdx.x;
    const int lane = tid & 63;
    const int wave = tid >> 6;
    const int wr = wave >> 1, wc = wave & 1;
    const int m0 = blockIdx.x * 128;
    const int lrow = lane & 15, lkg = lane >> 4;
    const int sr = tid >> 3;
    const int sc = (tid & 7) * 8;

    f32x4 acc[4][4];
#pragma unroll
    for (int mi = 0; mi < 4; ++mi)
#pragma unroll
        for (int ni = 0; ni < 4; ++ni) acc[mi][ni] = (f32x4){0.f, 0.f, 0.f, 0.f};

    for (int t = 0; t < 4; ++t) {
        const int k0 = t * 64;
#pragma unroll
        for (int i = 0; i < 4; ++i) {
            int r = i * 32 + sr;
            float4 v0 = make_float4(0.f, 0.f, 0.f, 0.f), v1 = v0;
            if (m0 + r < M) {
                const float* p = &A[(size_t)(m0 + r) * 256 + k0 + sc];
                v0 = *(const float4*)p;
                v1 = *(const float4*)(p + 4);
            }
            uint4 pk = make_uint4(pack2(v0.x, v0.y), pack2(v0.z, v0.w),
                                  pack2(v1.x, v1.y), pack2(v1.z, v1.w));
            uint32_t off = (uint32_t)(r * 128 + sc * 2);
            *(uint4*)(As + (off ^ ((r & 7) << 4))) = pk;
        }
#pragma unroll
        for (int i = 0; i < 4; ++i) {
            int r = i * 32 + sr;
            const float* p = &W[(size_t)r * 256 + k0 + sc];
            float4 v0 = *(const float4*)p;
            float4 v1 = *(const float4*)(p + 4);
            uint4 pk = make_uint4(pack2(v0.x, v0.y), pack2(v0.z, v0.w),
                                  pack2(v1.x, v1.y), pack2(v1.z, v1.w));
            uint32_t off = (uint32_t)(r * 128 + sc * 2);
            *(uint4*)(Bs + (off ^ ((r & 7) << 4))) = pk;
        }
        __syncthreads();
#pragma unroll
        for (int ks = 0; ks < 2; ++ks) {
            bf16x8 af[4], bfr[4];
#pragma unroll
            for (int mi = 0; mi < 4; ++mi) {
                int r = wr * 64 + mi * 16 + lrow;
                uint32_t off = (uint32_t)(r * 128 + ks * 64 + lkg * 16);
                af[mi] = *(const bf16x8*)(As + (off ^ ((r & 7) << 4)));
            }
#pragma unroll
            for (int ni = 0; ni < 4; ++ni) {
                int r = wc * 64 + ni * 16 + lrow;
                uint32_t off = (uint32_t)(r * 128 + ks * 64 + lkg * 16);
                bfr[ni] = *(const bf16x8*)(Bs + (off ^ ((r & 7) << 4)));
            }
#pragma unroll
            for (int mi = 0; mi < 4; ++mi)
#pragma unroll
                for (int ni = 0; ni < 4; ++ni)
                    acc[mi][ni] = __builtin_amdgcn_mfma_f32_16x16x32_bf16(
                        af[mi], bfr[ni], acc[mi][ni], 0, 0, 0);
        }
        __syncthreads();
    }
#pragma unroll
    for (int mi = 0; mi < 4; ++mi) {
#pragma unroll
        for (int ni = 0; ni < 4; ++ni) {
            int n = wc * 64 + ni * 16 + lrow;
            float bv = bias[n];
#pragma unroll
            for (int q = 0; q < 4; ++q) {
                float v = fmaxf(acc[mi][ni][q] + bv, 0.f);
                float vp = __shfl_xor(v, 1);
                int m = m0 + wr * 64 + mi * 16 + lkg * 4 + q;
                if (!(lane & 1) && m < M)
                    hb[(size_t)m * 64 + (n >> 1)] = pack2(v, vp);
            }
        }
    }
}

// ---------------- GEMM2 (MFMA bf16) + fused log_softmax ----------------
// A: M x 128 bf16 (u32-packed). W: 64 x 128 fp32. 128x64 tile, 4 waves 2x2 (64x32 each).
__global__ __launch_bounds__(256) void k_gemm2(const uint32_t* __restrict__ Abf,
                                               const float* __restrict__ W,
                                               const float* __restrict__ bias,
                                               float* __restrict__ out, int M) {
    __shared__ char As[128 * 128];
    __shared__ char Bs[64 * 128];
    __shared__ float redmax[2][128];
    __shared__ float redsum[2][128];
    const int tid = threadIdx.x;
    const int lane = tid & 63;
    const int wave = tid >> 6;
    const int wr = wave >> 1, wc = wave & 1;
    const int m0 = blockIdx.x * 128;
    const int lrow = lane & 15, lkg = lane >> 4;

    f32x4 acc[4][2];
#pragma unroll
    for (int mi = 0; mi < 4; ++mi)
#pragma unroll
        for (int ni = 0; ni < 2; ++ni) acc[mi][ni] = (f32x4){0.f, 0.f, 0.f, 0.f};

    for (int t = 0; t < 2; ++t) {
#pragma unroll
        for (int i = 0; i < 4; ++i) {
            int r = i * 32 + (tid >> 3);
            uint4 v = make_uint4(0u, 0u, 0u, 0u);
            if (m0 + r < M)
                v = *(const uint4*)&Abf[(size_t)(m0 + r) * 64 + t * 32 + (tid & 7) * 4];
            uint32_t off = (uint32_t)(r * 128 + (tid & 7) * 16);
            *(uint4*)(As + (off ^ ((r & 7) << 4))) = v;
        }
#pragma unroll
        for (int i = 0; i < 2; ++i) {
            int r = i * 32 + (tid >> 3);
            const float* p = &W[(size_t)r * 128 + t * 64 + (tid & 7) * 8];
            float4 v0 = *(const float4*)p, v1 = *(const float4*)(p + 4);
            uint4 pk = make_uint4(pack2(v0.x, v0.y), pack2(v0.z, v0.w),
                                  pack2(v1.x, v1.y), pack2(v1.z, v1.w));
            uint32_t off = (uint32_t)(r * 128 + (tid & 7) * 16);
            *(uint4*)(Bs + (off ^ ((r & 7) << 4))) = pk;
        }
        __syncthreads();
#pragma unroll
        for (int ks = 0; ks < 2; ++ks) {
            bf16x8 af[4], bfr[2];
#pragma unroll
            for (int mi = 0; mi < 4; ++mi) {
                int r = wr * 64 + mi * 16 + lrow;
                uint32_t off = (uint32_t)(r * 128 + ks * 64 + lkg * 16);
                af[mi] = *(const bf16x8*)(As + (off ^ ((r & 7) << 4)));
            }
#pragma unroll
            for (int ni = 0; ni < 2; ++ni) {
                int r = wc * 32 + ni * 16 + lrow;
                uint32_t off = (uint32_t)(r * 128 + ks * 64 + lkg * 16);
                bfr[ni] = *(const bf16x8*)(Bs + (off ^ ((r & 7) << 4)));
            }
#pragma unroll
            for (int mi = 0; mi < 4; ++mi)
#pragma unroll
                for (int ni = 0; ni < 2; ++ni)
                    acc[mi][ni] = __builtin_amdgcn_mfma_f32_16x16x32_bf16(
                        af[mi], bfr[ni], acc[mi][ni], 0, 0, 0);
        }
        __syncthreads();
    }

    // epilogue: bias, then row-wise log_softmax over 64 cols (split across wc=0/1)
    float vb[4][2][4];
#pragma unroll
    for (int mi = 0; mi < 4; ++mi)
#pragma unroll
        for (int ni = 0; ni < 2; ++ni) {
            float bv = bias[wc * 32 + ni * 16 + lrow];
#pragma unroll
            for (int q = 0; q < 4; ++q) vb[mi][ni][q] = acc[mi][ni][q] + bv;
        }
    // partial row max over this wave's 32 cols
#pragma unroll
    for (int mi = 0; mi < 4; ++mi)
#pragma unroll
        for (int q = 0; q < 4; ++q) {
            float mx = fmaxf(vb[mi][0][q], vb[mi][1][q]);
#pragma unroll
            for (int o = 1; o < 16; o <<= 1) mx = fmaxf(mx, __shfl_xor(mx, o));
            if (lrow == 0) redmax[wc][wr * 64 + mi * 16 + lkg * 4 + q] = mx;
        }
    __syncthreads();
    float fmv[4][4];
#pragma unroll
    for (int mi = 0; mi < 4; ++mi)
#pragma unroll
        for (int q = 0; q < 4; ++q) {
            int rl = wr * 64 + mi * 16 + lkg * 4 + q;
            float fm = fmaxf(redmax[0][rl], redmax[1][rl]);
            fmv[mi][q] = fm;
            float e = expf(vb[mi][0][q] - fm) + expf(vb[mi][1][q] - fm);
#pragma unroll
            for (int o = 1; o < 16; o <<= 1) e += __shfl_xor(e, o);
            if (lrow == 0) redsum[wc][rl] = e;
        }
    __syncthreads();
#pragma unroll
    for (int mi = 0; mi < 4; ++mi)
#pragma unroll
        for (int q = 0; q < 4; ++q) {
            int rl = wr * 64 + mi * 16 + lkg * 4 + q;
            int m = m0 + rl;
            if (m < M) {
                float ls = logf(redsum[0][rl] + redsum[1][rl]) + fmv[mi][q];
                out[(size_t)m * 64 + wc * 32 + lrow] = vb[mi][0][q] - ls;
                out[(size_t)m * 64 + wc * 32 + 16 + lrow] = vb[mi][1][q] - ls;
            }
        }
}

// ---------------- per-node gate scalars (bf16 h) ----------------
__global__ void k_ab(const uint32_t* __restrict__ hbv, const float* __restrict__ gw,
                     const float* __restrict__ gb, int layer,
                     const float* __restrict__ dinv,
                     float* __restrict__ av, float2* __restrict__ bd, int N) {
    int wid = threadIdx.x >> 6, lane = threadIdx.x & 63;
    int i = blockIdx.x * 4 + wid;
    if (i >= N) return;
    uint32_t u = hbv[(size_t)i * 64 + lane];
    float hx = bflo(u), hy = bfhi(u);
    float2 wi = *(const float2*)&gw[lane * 2];
    float2 wj = *(const float2*)&gw[128 + lane * 2];
    float pa = hx * wi.x + hy * wi.y;
    float pb = hx * wj.x + hy * wj.y;
    for (int o = 1; o < 64; o <<= 1) {
        pa += __shfl_xor(pa, o);
        pb += __shfl_xor(pb, o);
    }
    if (lane == 0) {
        av[i] = pa + gb[layer];
        bd[i] = make_float2(pb, dinv[i]);
    }
}

// ---------------- per-edge weights: ew[p] = tanh(a_row + b_col) * dinv_col ----------------
__global__ void k_edgew(const int* __restrict__ rp, const int* __restrict__ ecol,
                        const float* __restrict__ av, const float2* __restrict__ bd,
                        float* __restrict__ ew, int N) {
    int wid = threadIdx.x >> 6, lane = threadIdx.x & 63;
    int i = blockIdx.x * 4 + wid;
    if (i >= N) return;
    float a_i = av[i];
    int p0 = rp[i], p1 = rp[i + 1];
    for (int p = p0 + lane; p < p1; p += 64) {
        int c = ecol[p];
        float2 t = bd[c];
        ew[p] = tanhf(a_i + t.x) * t.y;
    }
}

// ---------------- aggregation: scalar edge stream + coalesced row gather ----------------
__global__ __launch_bounds__(256) void k_agg(const uint32_t* __restrict__ hb,
                                             const uint32_t* __restrict__ raw,
                                             const int* __restrict__ rp,
                                             const int* __restrict__ ecol,
                                             const float* __restrict__ ew,
                                             const float* __restrict__ dinv,
                                             uint32_t* __restrict__ hb_out, int N) {
    int wid = threadIdx.x >> 6, lane = threadIdx.x & 63;
    int i = blockIdx.x * 4 + wid;
    if (i >= N) return;
    int iu = __builtin_amdgcn_readfirstlane(i);
    int p0 = __builtin_amdgcn_readfirstlane(rp[iu]);
    int p1 = __builtin_amdgcn_readfirstlane(rp[iu + 1]);
    float acc0 = 0.f, acc1 = 0.f;
    int p = p0;
    for (; p + 4 <= p1; p += 4) {
        int c0 = ecol[p + 0], c1 = ecol[p + 1], c2 = ecol[p + 2], c3 = ecol[p + 3];
        float w0 = ew[p + 0], w1 = ew[p + 1], w2 = ew[p + 2], w3 = ew[p + 3];
        uint32_t u0 = hb[(size_t)c0 * 64 + lane];
        uint32_t u1 = hb[(size_t)c1 * 64 + lane];
        uint32_t u2 = hb[(size_t)c2 * 64 + lane];
        uint32_t u3 = hb[(size_t)c3 * 64 + lane];
        acc0 = fmaf(w0, bflo(u0), acc0); acc1 = fmaf(w0, bfhi(u0), acc1);
        acc0 = fmaf(w1, bflo(u1), acc0); acc1 = fmaf(w1, bfhi(u1), acc1);
        acc0 = fmaf(w2, bflo(u2), acc0); acc1 = fmaf(w2, bfhi(u2), acc1);
        acc0 = fmaf(w3, bflo(u3), acc0); acc1 = fmaf(w3, bfhi(u3), acc1);
    }
    for (; p < p1; ++p) {
        int c = ecol[p];
        float w = ew[p];
        uint32_t u = hb[(size_t)c * 64 + lane];
        acc0 = fmaf(w, bflo(u), acc0);
        acc1 = fmaf(w, bfhi(u), acc1);
    }
    float di = dinv[iu];
    uint32_t ru = raw[(size_t)i * 64 + lane];
    float o0 = EPSF * bflo(ru) + di * acc0;
    float o1 = EPSF * bfhi(ru) + di * acc1;
    hb_out[(size_t)i * 64 + lane] = pack2(o0, o1);
}

extern "C" void kernel_launch(void* const* d_in, const int* in_sizes, int n_in,
                              void* d_out, int out_size, void* d_ws, size_t ws_size,
                              hipStream_t stream) {
    const float* x = (const float*)d_in[0];
    const int* ei = (const int*)d_in[1];
    const float* t1w = (const float*)d_in[2];
    const float* t1b = (const float*)d_in[3];
    const float* gw = (const float*)d_in[4];
    const float* gb = (const float*)d_in[5];
    const float* t2w = (const float*)d_in[6];
    const float* t2b = (const float*)d_in[7];
    float* out = (float*)d_out;

    const int INC = 256;
    const int N = in_sizes[0] / INC;
    const int E = in_sizes[1] / 2;
    const int NB = (N + NPB - 1) >> SHB;
    const int nblk = (E + CHUNK - 1) / CHUNK;

    char* ws = (char*)d_ws;
    auto alloc = [&](size_t bytes) {
        char* p = ws;
        ws += (bytes + 255) & ~(size_t)255;
        return p;
    };
    int* flag = (int*)alloc(4);
    int* hist = (int*)alloc((size_t)NB * nblk * 4);
    int* btot = (int*)alloc((size_t)NB * 4);
    int* bbase = (int*)alloc((size_t)(NB + 1) * 4);
    uint32_t* ebuf = (uint32_t*)alloc((size_t)E * 4);
    int* rp = (int*)alloc((size_t)(N + 1) * 4);
    float* dinv = (float*)alloc((size_t)N * 4);
    int* ecol = (int*)alloc((size_t)E * 4);
    float* ewt = (float*)alloc((size_t)E * 4);
    float* av = (float*)alloc((size_t)N * 4);
    float2* bd = (float2*)alloc((size_t)N * 8);
    uint32_t* hb0 = (uint32_t*)alloc((size_t)N * 64 * 4);
    uint32_t* hb1 = (uint32_t*)alloc((size_t)N * 64 * 4);
    uint32_t* hb2 = (uint32_t*)alloc((size_t)N * 64 * 4);

    // ---- CSR build (no global atomics) ----
    k_detect<<<1, 256, 0, stream>>>(ei, flag);
    k_hist<<<nblk, 256, 0, stream>>>(ei, E, flag, hist, nblk, NB);
    k_scanA<<<NB, 64, 0, stream>>>(hist, nblk, btot);
    k_scanB<<<1, MAXNB, 0, stream>>>(btot, NB, bbase);
    k_binwrite<<<nblk, 256, 0, stream>>>(ei, E, flag, hist, bbase, ebuf, nblk, NB);
    k_csr<<<NB, 256, 0, stream>>>(ebuf, bbase, rp, dinv, ecol, N, E, NB);

    // ---- hb0 = relu(x @ t1_w^T + t1_b) (bf16, MFMA) ----
    k_gemm1<<<(N + 127) / 128, 256, 0, stream>>>(x, t1w, t1b, hb0, N);

    // ---- layer 0: hb0 -> hb1 ----
    k_ab<<<(N + 3) / 4, 256, 0, stream>>>(hb0, gw + 0 * 256, gb, 0, dinv, av, bd, N);
    k_edgew<<<(N + 3) / 4, 256, 0, stream>>>(rp, ecol, av, bd, ewt, N);
    k_agg<<<(N + 3) / 4, 256, 0, stream>>>(hb0, hb0, rp, ecol, ewt, dinv, hb1, N);
    // ---- layer 1: hb1 -> hb2 (raw = hb0) ----
    k_ab<<<(N + 3) / 4, 256, 0, stream>>>(hb1, gw + 1 * 256, gb, 1, dinv, av, bd, N);
    k_edgew<<<(N + 3) / 4, 256, 0, stream>>>(rp, ecol, av, bd, ewt, N);
    k_agg<<<(N + 3) / 4, 256, 0, stream>>>(hb1, hb0, rp, ecol, ewt, dinv, hb2, N);

    // ---- out = log_softmax(hb2 @ t2_w^T + t2_b) (MFMA, fused) ----
    k_gemm2<<<(N + 127) / 128, 256, 0, stream>>>(hb2, t2w, t2b, out, N);
}

// Round 6
// 236.540 us; speedup vs baseline: 1.1094x; 1.1094x over previous
//
#include <hip/hip_runtime.h>
#include <math.h>

#define EPSF 0.3f
#define NPB 128      // nodes per bucket
#define SHB 7        // log2(NPB)
#define MAXNB 512    // max buckets
#define CHUNK 16384  // edges per block in hist/binwrite

typedef __attribute__((ext_vector_type(8))) short bf16x8;
typedef __attribute__((ext_vector_type(4))) float f32x4;

// ---------------- bf16 helpers ----------------
__device__ __forceinline__ uint32_t f2bf(float f) {
    uint32_t u = __float_as_uint(f);
    return (u + 0x7fffu + ((u >> 16) & 1u)) >> 16;  // RNE
}
__device__ __forceinline__ uint32_t pack2(float lo, float hi) {
    return f2bf(lo) | (f2bf(hi) << 16);
}
__device__ __forceinline__ float bflo(uint32_t u) { return __uint_as_float(u << 16); }
__device__ __forceinline__ float bfhi(uint32_t u) { return __uint_as_float(u & 0xffff0000u); }

__device__ __forceinline__ int edge_at(const int* ei, int is64, size_t idx) {
    if (is64) return (int)((const long long*)ei)[idx];
    return ei[idx];
}

// per-block int32/int64 detection: sample odd dwords of this block's row slice
__device__ __forceinline__ int detect_is64(const int* ei, int base, int E) {
    __shared__ int s_nz;
    if (threadIdx.x == 0) s_nz = 0;
    __syncthreads();
    int lim = min(512, E - base);
    int nz = 0;
    for (int t = threadIdx.x; t < lim; t += 256)
        nz |= (ei[2 * (size_t)(base + t) + 1] != 0);
    if (nz) atomicOr(&s_nz, 1);
    __syncthreads();
    return s_nz == 0;
}

// ---------------- bucket histogram ----------------
__global__ __launch_bounds__(256) void k_hist(const int* __restrict__ ei, int E,
                                              int* __restrict__ hist, int nblk, int NB) {
    __shared__ int lh[MAXNB];
    int base = blockIdx.x * CHUNK;
    int is64 = detect_is64(ei, base, E);
    for (int b = threadIdx.x; b < NB; b += 256) lh[b] = 0;
    __syncthreads();
    for (int j = threadIdx.x; j < CHUNK; j += 256) {
        int e = base + j;
        if (e < E) {
            int r = edge_at(ei, is64, e);
            atomicAdd(&lh[r >> SHB], 1);
        }
    }
    __syncthreads();
    for (int b = threadIdx.x; b < NB; b += 256)
        hist[(size_t)b * nblk + blockIdx.x] = lh[b];
}

__global__ void k_scanA(int* __restrict__ hist, int nblk, int* __restrict__ btot) {
    int b = blockIdx.x;
    int lane = threadIdx.x;
    int run = 0;
    for (int seg = 0; seg < nblk; seg += 64) {
        int idx = seg + lane;
        int v = (idx < nblk) ? hist[(size_t)b * nblk + idx] : 0;
        int s = v;
        for (int o = 1; o < 64; o <<= 1) {
            int t = __shfl_up(s, o);
            if (lane >= o) s += t;
        }
        if (idx < nblk) hist[(size_t)b * nblk + idx] = run + s - v;
        run += __shfl(s, 63);
    }
    if (lane == 0) btot[b] = run;
}

__global__ void k_scanB(const int* __restrict__ btot, int NB, int* __restrict__ bbase) {
    __shared__ int s[MAXNB];
    int t = threadIdx.x;
    int v = (t < NB) ? btot[t] : 0;
    s[t] = v;
    __syncthreads();
    for (int o = 1; o < MAXNB; o <<= 1) {
        int x = (t >= o) ? s[t - o] : 0;
        __syncthreads();
        s[t] += x;
        __syncthreads();
    }
    if (t < NB) bbase[t] = s[t] - v;
    if (t == MAXNB - 1) bbase[NB] = s[t];
}

// packed ebuf entry: (r & 127) | (c << 7)
__global__ __launch_bounds__(256) void k_binwrite(const int* __restrict__ ei, int E,
                                                  const int* __restrict__ hist,
                                                  const int* __restrict__ bbase,
                                                  uint32_t* __restrict__ ebuf,
                                                  int nblk, int NB) {
    __shared__ int lcnt[MAXNB];
    int base = blockIdx.x * CHUNK;
    int is64 = detect_is64(ei, base, E);
    for (int b = threadIdx.x; b < NB; b += 256)
        lcnt[b] = bbase[b] + hist[(size_t)b * nblk + blockIdx.x];
    __syncthreads();
    for (int j = threadIdx.x; j < CHUNK; j += 256) {
        int e = base + j;
        if (e < E) {
            int r = edge_at(ei, is64, e);
            int c = edge_at(ei, is64, (size_t)E + e);
            int pos = atomicAdd(&lcnt[r >> SHB], 1);
            ebuf[pos] = (uint32_t)(r & (NPB - 1)) | ((uint32_t)c << SHB);
        }
    }
}

__global__ __launch_bounds__(256) void k_csr(const uint32_t* __restrict__ ebuf,
                                             const int* __restrict__ bbase,
                                             int* __restrict__ rp, float* __restrict__ dinv,
                                             int* __restrict__ ecol, int N, int E, int NB) {
    __shared__ int cnt[NPB];
    __shared__ int sc[NPB];
    __shared__ int cur[NPB];
    int b = blockIdx.x;
    int tid = threadIdx.x;
    int p0 = bbase[b], p1 = bbase[b + 1];
    int n0 = b << SHB;
    if (tid < NPB) cnt[tid] = 0;
    __syncthreads();
    for (int p = p0 + tid; p < p1; p += 256)
        atomicAdd(&cnt[ebuf[p] & (NPB - 1)], 1);
    __syncthreads();
    if (tid < NPB) sc[tid] = cnt[tid];
    __syncthreads();
    for (int o = 1; o < NPB; o <<= 1) {
        int v = (tid < NPB && tid >= o) ? sc[tid - o] : 0;
        __syncthreads();
        if (tid < NPB) sc[tid] += v;
        __syncthreads();
    }
    if (tid < NPB) {
        int off = sc[tid] - cnt[tid];
        cur[tid] = off;
        int node = n0 + tid;
        if (node < N) {
            rp[node] = p0 + off;
            int d = cnt[tid];
            dinv[node] = d > 0 ? rsqrtf((float)d) : 0.f;
        }
    }
    if (b == NB - 1 && tid == 0) rp[N] = E;
    __syncthreads();
    for (int p = p0 + tid; p < p1; p += 256) {
        uint32_t v = ebuf[p];
        int pos = p0 + atomicAdd(&cur[v & (NPB - 1)], 1);
        ecol[pos] = (int)(v >> SHB);
    }
}

// ---------------- GEMM1 (MFMA bf16): hb = relu(x @ t1_w^T + b) as bf16 ----------------
__global__ __launch_bounds__(256) void k_gemm1(const float* __restrict__ A,
                                               const float* __restrict__ W,
                                               const float* __restrict__ bias,
                                               uint32_t* __restrict__ hb, int M) {
    __shared__ char As[128 * 128];
    __shared__ char Bs[128 * 128];
    const int tid = threadIdx.x;
    const int lane = tid & 63;
    const int wave = tid >> 6;
    const int wr = wave >> 1, wc = wave & 1;
    const int m0 = blockIdx.x * 128;
    const int lrow = lane & 15, lkg = lane >> 4;
    const int sr = tid >> 3;
    const int sc = (tid & 7) * 8;

    f32x4 acc[4][4];
#pragma unroll
    for (int mi = 0; mi < 4; ++mi)
#pragma unroll
        for (int ni = 0; ni < 4; ++ni) acc[mi][ni] = (f32x4){0.f, 0.f, 0.f, 0.f};

    for (int t = 0; t < 4; ++t) {
        const int k0 = t * 64;
#pragma unroll
        for (int i = 0; i < 4; ++i) {
            int r = i * 32 + sr;
            float4 v0 = make_float4(0.f, 0.f, 0.f, 0.f), v1 = v0;
            if (m0 + r < M) {
                const float* p = &A[(size_t)(m0 + r) * 256 + k0 + sc];
                v0 = *(const float4*)p;
                v1 = *(const float4*)(p + 4);
            }
            uint4 pk = make_uint4(pack2(v0.x, v0.y), pack2(v0.z, v0.w),
                                  pack2(v1.x, v1.y), pack2(v1.z, v1.w));
            uint32_t off = (uint32_t)(r * 128 + sc * 2);
            *(uint4*)(As + (off ^ ((r & 7) << 4))) = pk;
        }
#pragma unroll
        for (int i = 0; i < 4; ++i) {
            int r = i * 32 + sr;
            const float* p = &W[(size_t)r * 256 + k0 + sc];
            float4 v0 = *(const float4*)p;
            float4 v1 = *(const float4*)(p + 4);
            uint4 pk = make_uint4(pack2(v0.x, v0.y), pack2(v0.z, v0.w),
                                  pack2(v1.x, v1.y), pack2(v1.z, v1.w));
            uint32_t off = (uint32_t)(r * 128 + sc * 2);
            *(uint4*)(Bs + (off ^ ((r & 7) << 4))) = pk;
        }
        __syncthreads();
#pragma unroll
        for (int ks = 0; ks < 2; ++ks) {
            bf16x8 af[4], bfr[4];
#pragma unroll
            for (int mi = 0; mi < 4; ++mi) {
                int r = wr * 64 + mi * 16 + lrow;
                uint32_t off = (uint32_t)(r * 128 + ks * 64 + lkg * 16);
                af[mi] = *(const bf16x8*)(As + (off ^ ((r & 7) << 4)));
            }
#pragma unroll
            for (int ni = 0; ni < 4; ++ni) {
                int r = wc * 64 + ni * 16 + lrow;
                uint32_t off = (uint32_t)(r * 128 + ks * 64 + lkg * 16);
                bfr[ni] = *(const bf16x8*)(Bs + (off ^ ((r & 7) << 4)));
            }
#pragma unroll
            for (int mi = 0; mi < 4; ++mi)
#pragma unroll
                for (int ni = 0; ni < 4; ++ni)
                    acc[mi][ni] = __builtin_amdgcn_mfma_f32_16x16x32_bf16(
                        af[mi], bfr[ni], acc[mi][ni], 0, 0, 0);
        }
        __syncthreads();
    }
#pragma unroll
    for (int mi = 0; mi < 4; ++mi) {
#pragma unroll
        for (int ni = 0; ni < 4; ++ni) {
            int n = wc * 64 + ni * 16 + lrow;
            float bv = bias[n];
#pragma unroll
            for (int q = 0; q < 4; ++q) {
                float v = fmaxf(acc[mi][ni][q] + bv, 0.f);
                float vp = __shfl_xor(v, 1);
                int m = m0 + wr * 64 + mi * 16 + lkg * 4 + q;
                if (!(lane & 1) && m < M)
                    hb[(size_t)m * 64 + (n >> 1)] = pack2(v, vp);
            }
        }
    }
}

// ---------------- GEMM2 (MFMA bf16) + fused log_softmax ----------------
__global__ __launch_bounds__(256) void k_gemm2(const uint32_t* __restrict__ Abf,
                                               const float* __restrict__ W,
                                               const float* __restrict__ bias,
                                               float* __restrict__ out, int M) {
    __shared__ char As[128 * 128];
    __shared__ char Bs[64 * 128];
    __shared__ float redmax[2][128];
    __shared__ float redsum[2][128];
    const int tid = threadIdx.x;
    const int lane = tid & 63;
    const int wave = tid >> 6;
    const int wr = wave >> 1, wc = wave & 1;
    const int m0 = blockIdx.x * 128;
    const int lrow = lane & 15, lkg = lane >> 4;

    f32x4 acc[4][2];
#pragma unroll
    for (int mi = 0; mi < 4; ++mi)
#pragma unroll
        for (int ni = 0; ni < 2; ++ni) acc[mi][ni] = (f32x4){0.f, 0.f, 0.f, 0.f};

    for (int t = 0; t < 2; ++t) {
#pragma unroll
        for (int i = 0; i < 4; ++i) {
            int r = i * 32 + (tid >> 3);
            uint4 v = make_uint4(0u, 0u, 0u, 0u);
            if (m0 + r < M)
                v = *(const uint4*)&Abf[(size_t)(m0 + r) * 64 + t * 32 + (tid & 7) * 4];
            uint32_t off = (uint32_t)(r * 128 + (tid & 7) * 16);
            *(uint4*)(As + (off ^ ((r & 7) << 4))) = v;
        }
#pragma unroll
        for (int i = 0; i < 2; ++i) {
            int r = i * 32 + (tid >> 3);
            const float* p = &W[(size_t)r * 128 + t * 64 + (tid & 7) * 8];
            float4 v0 = *(const float4*)p, v1 = *(const float4*)(p + 4);
            uint4 pk = make_uint4(pack2(v0.x, v0.y), pack2(v0.z, v0.w),
                                  pack2(v1.x, v1.y), pack2(v1.z, v1.w));
            uint32_t off = (uint32_t)(r * 128 + (tid & 7) * 16);
            *(uint4*)(Bs + (off ^ ((r & 7) << 4))) = pk;
        }
        __syncthreads();
#pragma unroll
        for (int ks = 0; ks < 2; ++ks) {
            bf16x8 af[4], bfr[2];
#pragma unroll
            for (int mi = 0; mi < 4; ++mi) {
                int r = wr * 64 + mi * 16 + lrow;
                uint32_t off = (uint32_t)(r * 128 + ks * 64 + lkg * 16);
                af[mi] = *(const bf16x8*)(As + (off ^ ((r & 7) << 4)));
            }
#pragma unroll
            for (int ni = 0; ni < 2; ++ni) {
                int r = wc * 32 + ni * 16 + lrow;
                uint32_t off = (uint32_t)(r * 128 + ks * 64 + lkg * 16);
                bfr[ni] = *(const bf16x8*)(Bs + (off ^ ((r & 7) << 4)));
            }
#pragma unroll
            for (int mi = 0; mi < 4; ++mi)
#pragma unroll
                for (int ni = 0; ni < 2; ++ni)
                    acc[mi][ni] = __builtin_amdgcn_mfma_f32_16x16x32_bf16(
                        af[mi], bfr[ni], acc[mi][ni], 0, 0, 0);
        }
        __syncthreads();
    }

    float vb[4][2][4];
#pragma unroll
    for (int mi = 0; mi < 4; ++mi)
#pragma unroll
        for (int ni = 0; ni < 2; ++ni) {
            float bv = bias[wc * 32 + ni * 16 + lrow];
#pragma unroll
            for (int q = 0; q < 4; ++q) vb[mi][ni][q] = acc[mi][ni][q] + bv;
        }
#pragma unroll
    for (int mi = 0; mi < 4; ++mi)
#pragma unroll
        for (int q = 0; q < 4; ++q) {
            float mx = fmaxf(vb[mi][0][q], vb[mi][1][q]);
#pragma unroll
            for (int o = 1; o < 16; o <<= 1) mx = fmaxf(mx, __shfl_xor(mx, o));
            if (lrow == 0) redmax[wc][wr * 64 + mi * 16 + lkg * 4 + q] = mx;
        }
    __syncthreads();
    float fmv[4][4];
#pragma unroll
    for (int mi = 0; mi < 4; ++mi)
#pragma unroll
        for (int q = 0; q < 4; ++q) {
            int rl = wr * 64 + mi * 16 + lkg * 4 + q;
            float fm = fmaxf(redmax[0][rl], redmax[1][rl]);
            fmv[mi][q] = fm;
            float e = expf(vb[mi][0][q] - fm) + expf(vb[mi][1][q] - fm);
#pragma unroll
            for (int o = 1; o < 16; o <<= 1) e += __shfl_xor(e, o);
            if (lrow == 0) redsum[wc][rl] = e;
        }
    __syncthreads();
#pragma unroll
    for (int mi = 0; mi < 4; ++mi)
#pragma unroll
        for (int q = 0; q < 4; ++q) {
            int rl = wr * 64 + mi * 16 + lkg * 4 + q;
            int m = m0 + rl;
            if (m < M) {
                float ls = logf(redsum[0][rl] + redsum[1][rl]) + fmv[mi][q];
                out[(size_t)m * 64 + wc * 32 + lrow] = vb[mi][0][q] - ls;
                out[(size_t)m * 64 + wc * 32 + 16 + lrow] = vb[mi][1][q] - ls;
            }
        }
}

// ---------------- per-node gate scalars (layer 0 only; layer 1 fused into agg0) ----------
__global__ void k_ab(const uint32_t* __restrict__ hbv, const float* __restrict__ gw,
                     const float* __restrict__ gb, int layer,
                     const float* __restrict__ dinv,
                     float* __restrict__ av, float2* __restrict__ bd, int N) {
    int wid = threadIdx.x >> 6, lane = threadIdx.x & 63;
    int i = blockIdx.x * 4 + wid;
    if (i >= N) return;
    uint32_t u = hbv[(size_t)i * 64 + lane];
    float hx = bflo(u), hy = bfhi(u);
    float2 wi = *(const float2*)&gw[lane * 2];
    float2 wj = *(const float2*)&gw[128 + lane * 2];
    float pa = hx * wi.x + hy * wi.y;
    float pb = hx * wj.x + hy * wj.y;
    for (int o = 1; o < 64; o <<= 1) {
        pa += __shfl_xor(pa, o);
        pb += __shfl_xor(pb, o);
    }
    if (lane == 0) {
        av[i] = pa + gb[layer];
        bd[i] = make_float2(pb, dinv[i]);
    }
}

// ---------------- aggregation ----------------
// wave per node. Phase A: vector weight compute, pack (w_bf16<<16 | c).
// Phase B: 4 edges/iter — 16-lane groups each gather uint4 (16B) of one row.
// Phase C: cross-group reduce. Phase D: write (lanes 0-15, uint4).
// Phase E (FUSE_AB): compute next layer's av/bd from the output row.
template <bool FUSE_AB, bool RAW_NT>
__global__ __launch_bounds__(256) void k_agg(const uint32_t* __restrict__ hb,
                                             const uint32_t* __restrict__ raw,
                                             const int* __restrict__ rp,
                                             const int* __restrict__ ecol,
                                             const float* __restrict__ av,
                                             const float2* __restrict__ bd,
                                             const float* __restrict__ dinv,
                                             uint32_t* __restrict__ hb_out,
                                             const float* __restrict__ gw_next,
                                             const float* __restrict__ gb_next,
                                             float* __restrict__ av_out,
                                             float2* __restrict__ bd_out, int N) {
    int wid = threadIdx.x >> 6, lane = threadIdx.x & 63;
    int i = blockIdx.x * 4 + wid;
    if (i >= N) return;
    int iu = __builtin_amdgcn_readfirstlane(i);
    int p0 = __builtin_amdgcn_readfirstlane(rp[iu]);
    int p1 = __builtin_amdgcn_readfirstlane(rp[iu + 1]);
    float a_i = av[iu];
    float di = dinv[iu];
    const int lg = lane >> 4;   // edge sub-slot
    const int ll = lane & 15;   // channel quad

    float acc[8];
#pragma unroll
    for (int j = 0; j < 8; ++j) acc[j] = 0.f;

    for (int b0 = p0; b0 < p1; b0 += 64) {
        int cnt = min(64, p1 - b0);
        // Phase A: vector weight compute for this batch
        uint32_t wc = 0u;
        if (lane < cnt) {
            int c = __builtin_nontemporal_load(&ecol[b0 + lane]);
            float2 t = bd[c];
            float w = tanhf(a_i + t.x) * t.y;
            wc = (f2bf(w) << 16) | (uint32_t)c;
        }
        // Phase B: 4 edges per iteration
        for (int k = 0; k < cnt; k += 4) {
            uint32_t wcx = __builtin_amdgcn_ds_bpermute((k + lg) << 2, (int)wc);
            float w = bfhi(wcx);           // 0 for out-of-range slots
            int c = (int)(wcx & 0xffffu);
            uint4 u = *((const uint4*)(hb + (size_t)c * 64) + ll);
            acc[0] = fmaf(w, bflo(u.x), acc[0]); acc[1] = fmaf(w, bfhi(u.x), acc[1]);
            acc[2] = fmaf(w, bflo(u.y), acc[2]); acc[3] = fmaf(w, bfhi(u.y), acc[3]);
            acc[4] = fmaf(w, bflo(u.z), acc[4]); acc[5] = fmaf(w, bfhi(u.z), acc[5]);
            acc[6] = fmaf(w, bflo(u.w), acc[6]); acc[7] = fmaf(w, bfhi(u.w), acc[7]);
        }
    }
    // Phase C: reduce across the 4 edge sub-slots
#pragma unroll
    for (int j = 0; j < 8; ++j) {
        acc[j] += __shfl_xor(acc[j], 16);
        acc[j] += __shfl_xor(acc[j], 32);
    }
    // Phase D (+E): lanes 0-15 own 8 channels each
    if (lane < 16) {
        const uint32_t* rpt = raw + (size_t)i * 64 + ll * 4;
        uint32_t r0, r1, r2, r3;
        if (RAW_NT) {
            r0 = __builtin_nontemporal_load(rpt + 0);
            r1 = __builtin_nontemporal_load(rpt + 1);
            r2 = __builtin_nontemporal_load(rpt + 2);
            r3 = __builtin_nontemporal_load(rpt + 3);
        } else {
            r0 = rpt[0]; r1 = rpt[1]; r2 = rpt[2]; r3 = rpt[3];
        }
        float o[8];
        o[0] = EPSF * bflo(r0) + di * acc[0]; o[1] = EPSF * bfhi(r0) + di * acc[1];
        o[2] = EPSF * bflo(r1) + di * acc[2]; o[3] = EPSF * bfhi(r1) + di * acc[3];
        o[4] = EPSF * bflo(r2) + di * acc[4]; o[5] = EPSF * bfhi(r2) + di * acc[5];
        o[6] = EPSF * bflo(r3) + di * acc[6]; o[7] = EPSF * bfhi(r3) + di * acc[7];
        uint4 w4;
        w4.x = pack2(o[0], o[1]); w4.y = pack2(o[2], o[3]);
        w4.z = pack2(o[4], o[5]); w4.w = pack2(o[6], o[7]);
        *((uint4*)(hb_out + (size_t)i * 64) + ll) = w4;
        if (FUSE_AB) {
            float pa = 0.f, pb = 0.f;
#pragma unroll
            for (int j = 0; j < 8; ++j) {
                int ch = ll * 8 + j;
                pa = fmaf(o[j], gw_next[ch], pa);
                pb = fmaf(o[j], gw_next[128 + ch], pb);
            }
#pragma unroll
            for (int off = 1; off < 16; off <<= 1) {
                pa += __shfl_xor(pa, off);
                pb += __shfl_xor(pb, off);
            }
            if (ll == 0) {
                av_out[i] = pa + gb_next[0];
                bd_out[i] = make_float2(pb, di);
            }
        }
    }
}

extern "C" void kernel_launch(void* const* d_in, const int* in_sizes, int n_in,
                              void* d_out, int out_size, void* d_ws, size_t ws_size,
                              hipStream_t stream) {
    const float* x = (const float*)d_in[0];
    const int* ei = (const int*)d_in[1];
    const float* t1w = (const float*)d_in[2];
    const float* t1b = (const float*)d_in[3];
    const float* gw = (const float*)d_in[4];
    const float* gb = (const float*)d_in[5];
    const float* t2w = (const float*)d_in[6];
    const float* t2b = (const float*)d_in[7];
    float* out = (float*)d_out;

    const int INC = 256;
    const int N = in_sizes[0] / INC;
    const int E = in_sizes[1] / 2;
    const int NB = (N + NPB - 1) >> SHB;
    const int nblk = (E + CHUNK - 1) / CHUNK;

    char* ws = (char*)d_ws;
    auto alloc = [&](size_t bytes) {
        char* p = ws;
        ws += (bytes + 255) & ~(size_t)255;
        return p;
    };
    int* hist = (int*)alloc((size_t)NB * nblk * 4);
    int* btot = (int*)alloc((size_t)NB * 4);
    int* bbase = (int*)alloc((size_t)(NB + 1) * 4);
    uint32_t* ebuf = (uint32_t*)alloc((size_t)E * 4);
    int* rp = (int*)alloc((size_t)(N + 1) * 4);
    float* dinv = (float*)alloc((size_t)N * 4);
    int* ecol = (int*)alloc((size_t)E * 4);
    float* av0 = (float*)alloc((size_t)N * 4);
    float* av1 = (float*)alloc((size_t)N * 4);
    float2* bd0 = (float2*)alloc((size_t)N * 8);
    float2* bd1 = (float2*)alloc((size_t)N * 8);
    uint32_t* hb0 = (uint32_t*)alloc((size_t)N * 64 * 4);
    uint32_t* hb1 = (uint32_t*)alloc((size_t)N * 64 * 4);
    uint32_t* hb2 = (uint32_t*)alloc((size_t)N * 64 * 4);

    // ---- CSR build (no global atomics, per-block dtype detect) ----
    k_hist<<<nblk, 256, 0, stream>>>(ei, E, hist, nblk, NB);
    k_scanA<<<NB, 64, 0, stream>>>(hist, nblk, btot);
    k_scanB<<<1, MAXNB, 0, stream>>>(btot, NB, bbase);
    k_binwrite<<<nblk, 256, 0, stream>>>(ei, E, hist, bbase, ebuf, nblk, NB);
    k_csr<<<NB, 256, 0, stream>>>(ebuf, bbase, rp, dinv, ecol, N, E, NB);

    // ---- hb0 = relu(x @ t1_w^T + t1_b) (bf16, MFMA) ----
    k_gemm1<<<(N + 127) / 128, 256, 0, stream>>>(x, t1w, t1b, hb0, N);

    // ---- layer 0 gate scalars ----
    k_ab<<<(N + 3) / 4, 256, 0, stream>>>(hb0, gw + 0 * 256, gb, 0, dinv, av0, bd0, N);
    // ---- layer 0: hb0 -> hb1, fused layer-1 ab ----
    k_agg<true, false><<<(N + 3) / 4, 256, 0, stream>>>(
        hb0, hb0, rp, ecol, av0, bd0, dinv, hb1, gw + 1 * 256, gb + 1, av1, bd1, N);
    // ---- layer 1: hb1 -> hb2 (raw = hb0, nontemporal) ----
    k_agg<false, true><<<(N + 3) / 4, 256, 0, stream>>>(
        hb1, hb0, rp, ecol, av1, bd1, dinv, hb2, nullptr, nullptr, nullptr, nullptr, N);

    // ---- out = log_softmax(hb2 @ t2_w^T + t2_b) (MFMA, fused) ----
    k_gemm2<<<(N + 127) / 128, 256, 0, stream>>>(hb2, t2w, t2b, out, N);
}

// Round 7
// 205.092 us; speedup vs baseline: 1.2795x; 1.1533x over previous
//
#include <hip/hip_runtime.h>
#include <math.h>

#define EPSF 0.3f
#define NPB 128      // nodes per bucket
#define SHB 7        // log2(NPB)
#define MAXNB 512    // max buckets
#define CHUNK 4096   // edges per block in hist/binwrite (391 blocks -> all CUs busy)

typedef __attribute__((ext_vector_type(8))) short bf16x8;
typedef __attribute__((ext_vector_type(4))) float f32x4;

// ---------------- bf16 helpers ----------------
__device__ __forceinline__ uint32_t f2bf(float f) {
    uint32_t u = __float_as_uint(f);
    return (u + 0x7fffu + ((u >> 16) & 1u)) >> 16;  // RNE
}
__device__ __forceinline__ uint32_t pack2(float lo, float hi) {
    return f2bf(lo) | (f2bf(hi) << 16);
}
__device__ __forceinline__ float bflo(uint32_t u) { return __uint_as_float(u << 16); }
__device__ __forceinline__ float bfhi(uint32_t u) { return __uint_as_float(u & 0xffff0000u); }

// fast tanh: 1 - 2/(e^{2x}+1); v_exp-based, |err| ~1e-6, saturates correctly
__device__ __forceinline__ float fast_tanh(float x) {
    float e = __expf(2.f * x);
    return 1.f - 2.f * __builtin_amdgcn_rcpf(e + 1.f);
}

__device__ __forceinline__ int edge_at(const int* ei, int is64, size_t idx) {
    if (is64) return (int)((const long long*)ei)[idx];
    return ei[idx];
}

// per-block int32/int64 detection: sample odd dwords of this block's row slice
__device__ __forceinline__ int detect_is64(const int* ei, int base, int E) {
    __shared__ int s_nz;
    if (threadIdx.x == 0) s_nz = 0;
    __syncthreads();
    int lim = min(512, E - base);
    int nz = 0;
    for (int t = threadIdx.x; t < lim; t += 256)
        nz |= (ei[2 * (size_t)(base + t) + 1] != 0);
    if (nz) atomicOr(&s_nz, 1);
    __syncthreads();
    return s_nz == 0;
}

// ---------------- bucket histogram ----------------
__global__ __launch_bounds__(256) void k_hist(const int* __restrict__ ei, int E,
                                              int* __restrict__ hist, int nblk, int NB) {
    __shared__ int lh[MAXNB];
    int base = blockIdx.x * CHUNK;
    int is64 = detect_is64(ei, base, E);
    for (int b = threadIdx.x; b < NB; b += 256) lh[b] = 0;
    __syncthreads();
    for (int j = threadIdx.x; j < CHUNK; j += 256) {
        int e = base + j;
        if (e < E) {
            int r = edge_at(ei, is64, e);
            atomicAdd(&lh[r >> SHB], 1);
        }
    }
    __syncthreads();
    for (int b = threadIdx.x; b < NB; b += 256)
        hist[(size_t)b * nblk + blockIdx.x] = lh[b];
}

__global__ void k_scanA(int* __restrict__ hist, int nblk, int* __restrict__ btot) {
    int b = blockIdx.x;
    int lane = threadIdx.x;
    int run = 0;
    for (int seg = 0; seg < nblk; seg += 64) {
        int idx = seg + lane;
        int v = (idx < nblk) ? hist[(size_t)b * nblk + idx] : 0;
        int s = v;
        for (int o = 1; o < 64; o <<= 1) {
            int t = __shfl_up(s, o);
            if (lane >= o) s += t;
        }
        if (idx < nblk) hist[(size_t)b * nblk + idx] = run + s - v;
        run += __shfl(s, 63);
    }
    if (lane == 0) btot[b] = run;
}

__global__ void k_scanB(const int* __restrict__ btot, int NB, int* __restrict__ bbase) {
    __shared__ int s[MAXNB];
    int t = threadIdx.x;
    int v = (t < NB) ? btot[t] : 0;
    s[t] = v;
    __syncthreads();
    for (int o = 1; o < MAXNB; o <<= 1) {
        int x = (t >= o) ? s[t - o] : 0;
        __syncthreads();
        s[t] += x;
        __syncthreads();
    }
    if (t < NB) bbase[t] = s[t] - v;
    if (t == MAXNB - 1) bbase[NB] = s[t];
}

// packed ebuf entry: (r & 127) | (c << 7)
__global__ __launch_bounds__(256) void k_binwrite(const int* __restrict__ ei, int E,
                                                  const int* __restrict__ hist,
                                                  const int* __restrict__ bbase,
                                                  uint32_t* __restrict__ ebuf,
                                                  int nblk, int NB) {
    __shared__ int lcnt[MAXNB];
    int base = blockIdx.x * CHUNK;
    int is64 = detect_is64(ei, base, E);
    for (int b = threadIdx.x; b < NB; b += 256)
        lcnt[b] = bbase[b] + hist[(size_t)b * nblk + blockIdx.x];
    __syncthreads();
    for (int j = threadIdx.x; j < CHUNK; j += 256) {
        int e = base + j;
        if (e < E) {
            int r = edge_at(ei, is64, e);
            int c = edge_at(ei, is64, (size_t)E + e);
            int pos = atomicAdd(&lcnt[r >> SHB], 1);
            ebuf[pos] = (uint32_t)(r & (NPB - 1)) | ((uint32_t)c << SHB);
        }
    }
}

__global__ __launch_bounds__(256) void k_csr(const uint32_t* __restrict__ ebuf,
                                             const int* __restrict__ bbase,
                                             int* __restrict__ rp, float* __restrict__ dinv,
                                             int* __restrict__ ecol, int N, int E, int NB) {
    __shared__ int cnt[NPB];
    __shared__ int sc[NPB];
    __shared__ int cur[NPB];
    int b = blockIdx.x;
    int tid = threadIdx.x;
    int p0 = bbase[b], p1 = bbase[b + 1];
    int n0 = b << SHB;
    if (tid < NPB) cnt[tid] = 0;
    __syncthreads();
    for (int p = p0 + tid; p < p1; p += 256)
        atomicAdd(&cnt[ebuf[p] & (NPB - 1)], 1);
    __syncthreads();
    if (tid < NPB) sc[tid] = cnt[tid];
    __syncthreads();
    for (int o = 1; o < NPB; o <<= 1) {
        int v = (tid < NPB && tid >= o) ? sc[tid - o] : 0;
        __syncthreads();
        if (tid < NPB) sc[tid] += v;
        __syncthreads();
    }
    if (tid < NPB) {
        int off = sc[tid] - cnt[tid];
        cur[tid] = off;
        int node = n0 + tid;
        if (node < N) {
            rp[node] = p0 + off;
            int d = cnt[tid];
            dinv[node] = d > 0 ? rsqrtf((float)d) : 0.f;
        }
    }
    if (b == NB - 1 && tid == 0) rp[N] = E;
    __syncthreads();
    for (int p = p0 + tid; p < p1; p += 256) {
        uint32_t v = ebuf[p];
        int pos = p0 + atomicAdd(&cur[v & (NPB - 1)], 1);
        ecol[pos] = (int)(v >> SHB);
    }
}

// ---------------- GEMM1 (MFMA bf16): hb = relu(x @ t1_w^T + b) as bf16 ----------------
__global__ __launch_bounds__(256) void k_gemm1(const float* __restrict__ A,
                                               const float* __restrict__ W,
                                               const float* __restrict__ bias,
                                               uint32_t* __restrict__ hb, int M) {
    __shared__ char As[128 * 128];
    __shared__ char Bs[128 * 128];
    const int tid = threadIdx.x;
    const int lane = tid & 63;
    const int wave = tid >> 6;
    const int wr = wave >> 1, wc = wave & 1;
    const int m0 = blockIdx.x * 128;
    const int lrow = lane & 15, lkg = lane >> 4;
    const int sr = tid >> 3;
    const int sc = (tid & 7) * 8;

    f32x4 acc[4][4];
#pragma unroll
    for (int mi = 0; mi < 4; ++mi)
#pragma unroll
        for (int ni = 0; ni < 4; ++ni) acc[mi][ni] = (f32x4){0.f, 0.f, 0.f, 0.f};

    for (int t = 0; t < 4; ++t) {
        const int k0 = t * 64;
#pragma unroll
        for (int i = 0; i < 4; ++i) {
            int r = i * 32 + sr;
            float4 v0 = make_float4(0.f, 0.f, 0.f, 0.f), v1 = v0;
            if (m0 + r < M) {
                const float* p = &A[(size_t)(m0 + r) * 256 + k0 + sc];
                v0 = *(const float4*)p;
                v1 = *(const float4*)(p + 4);
            }
            uint4 pk = make_uint4(pack2(v0.x, v0.y), pack2(v0.z, v0.w),
                                  pack2(v1.x, v1.y), pack2(v1.z, v1.w));
            uint32_t off = (uint32_t)(r * 128 + sc * 2);
            *(uint4*)(As + (off ^ ((r & 7) << 4))) = pk;
        }
#pragma unroll
        for (int i = 0; i < 4; ++i) {
            int r = i * 32 + sr;
            const float* p = &W[(size_t)r * 256 + k0 + sc];
            float4 v0 = *(const float4*)p;
            float4 v1 = *(const float4*)(p + 4);
            uint4 pk = make_uint4(pack2(v0.x, v0.y), pack2(v0.z, v0.w),
                                  pack2(v1.x, v1.y), pack2(v1.z, v1.w));
            uint32_t off = (uint32_t)(r * 128 + sc * 2);
            *(uint4*)(Bs + (off ^ ((r & 7) << 4))) = pk;
        }
        __syncthreads();
#pragma unroll
        for (int ks = 0; ks < 2; ++ks) {
            bf16x8 af[4], bfr[4];
#pragma unroll
            for (int mi = 0; mi < 4; ++mi) {
                int r = wr * 64 + mi * 16 + lrow;
                uint32_t off = (uint32_t)(r * 128 + ks * 64 + lkg * 16);
                af[mi] = *(const bf16x8*)(As + (off ^ ((r & 7) << 4)));
            }
#pragma unroll
            for (int ni = 0; ni < 4; ++ni) {
                int r = wc * 64 + ni * 16 + lrow;
                uint32_t off = (uint32_t)(r * 128 + ks * 64 + lkg * 16);
                bfr[ni] = *(const bf16x8*)(Bs + (off ^ ((r & 7) << 4)));
            }
#pragma unroll
            for (int mi = 0; mi < 4; ++mi)
#pragma unroll
                for (int ni = 0; ni < 4; ++ni)
                    acc[mi][ni] = __builtin_amdgcn_mfma_f32_16x16x32_bf16(
                        af[mi], bfr[ni], acc[mi][ni], 0, 0, 0);
        }
        __syncthreads();
    }
#pragma unroll
    for (int mi = 0; mi < 4; ++mi) {
#pragma unroll
        for (int ni = 0; ni < 4; ++ni) {
            int n = wc * 64 + ni * 16 + lrow;
            float bv = bias[n];
#pragma unroll
            for (int q = 0; q < 4; ++q) {
                float v = fmaxf(acc[mi][ni][q] + bv, 0.f);
                float vp = __shfl_xor(v, 1);
                int m = m0 + wr * 64 + mi * 16 + lkg * 4 + q;
                if (!(lane & 1) && m < M)
                    hb[(size_t)m * 64 + (n >> 1)] = pack2(v, vp);
            }
        }
    }
}

// ---------------- GEMM2 (MFMA bf16) + fused log_softmax ----------------
__global__ __launch_bounds__(256) void k_gemm2(const uint32_t* __restrict__ Abf,
                                               const float* __restrict__ W,
                                               const float* __restrict__ bias,
                                               float* __restrict__ out, int M) {
    __shared__ char As[128 * 128];
    __shared__ char Bs[64 * 128];
    __shared__ float redmax[2][128];
    __shared__ float redsum[2][128];
    const int tid = threadIdx.x;
    const int lane = tid & 63;
    const int wave = tid >> 6;
    const int wr = wave >> 1, wc = wave & 1;
    const int m0 = blockIdx.x * 128;
    const int lrow = lane & 15, lkg = lane >> 4;

    f32x4 acc[4][2];
#pragma unroll
    for (int mi = 0; mi < 4; ++mi)
#pragma unroll
        for (int ni = 0; ni < 2; ++ni) acc[mi][ni] = (f32x4){0.f, 0.f, 0.f, 0.f};

    for (int t = 0; t < 2; ++t) {
#pragma unroll
        for (int i = 0; i < 4; ++i) {
            int r = i * 32 + (tid >> 3);
            uint4 v = make_uint4(0u, 0u, 0u, 0u);
            if (m0 + r < M)
                v = *(const uint4*)&Abf[(size_t)(m0 + r) * 64 + t * 32 + (tid & 7) * 4];
            uint32_t off = (uint32_t)(r * 128 + (tid & 7) * 16);
            *(uint4*)(As + (off ^ ((r & 7) << 4))) = v;
        }
#pragma unroll
        for (int i = 0; i < 2; ++i) {
            int r = i * 32 + (tid >> 3);
            const float* p = &W[(size_t)r * 128 + t * 64 + (tid & 7) * 8];
            float4 v0 = *(const float4*)p, v1 = *(const float4*)(p + 4);
            uint4 pk = make_uint4(pack2(v0.x, v0.y), pack2(v0.z, v0.w),
                                  pack2(v1.x, v1.y), pack2(v1.z, v1.w));
            uint32_t off = (uint32_t)(r * 128 + (tid & 7) * 16);
            *(uint4*)(Bs + (off ^ ((r & 7) << 4))) = pk;
        }
        __syncthreads();
#pragma unroll
        for (int ks = 0; ks < 2; ++ks) {
            bf16x8 af[4], bfr[2];
#pragma unroll
            for (int mi = 0; mi < 4; ++mi) {
                int r = wr * 64 + mi * 16 + lrow;
                uint32_t off = (uint32_t)(r * 128 + ks * 64 + lkg * 16);
                af[mi] = *(const bf16x8*)(As + (off ^ ((r & 7) << 4)));
            }
#pragma unroll
            for (int ni = 0; ni < 2; ++ni) {
                int r = wc * 32 + ni * 16 + lrow;
                uint32_t off = (uint32_t)(r * 128 + ks * 64 + lkg * 16);
                bfr[ni] = *(const bf16x8*)(Bs + (off ^ ((r & 7) << 4)));
            }
#pragma unroll
            for (int mi = 0; mi < 4; ++mi)
#pragma unroll
                for (int ni = 0; ni < 2; ++ni)
                    acc[mi][ni] = __builtin_amdgcn_mfma_f32_16x16x32_bf16(
                        af[mi], bfr[ni], acc[mi][ni], 0, 0, 0);
        }
        __syncthreads();
    }

    float vb[4][2][4];
#pragma unroll
    for (int mi = 0; mi < 4; ++mi)
#pragma unroll
        for (int ni = 0; ni < 2; ++ni) {
            float bv = bias[wc * 32 + ni * 16 + lrow];
#pragma unroll
            for (int q = 0; q < 4; ++q) vb[mi][ni][q] = acc[mi][ni][q] + bv;
        }
#pragma unroll
    for (int mi = 0; mi < 4; ++mi)
#pragma unroll
        for (int q = 0; q < 4; ++q) {
            float mx = fmaxf(vb[mi][0][q], vb[mi][1][q]);
#pragma unroll
            for (int o = 1; o < 16; o <<= 1) mx = fmaxf(mx, __shfl_xor(mx, o));
            if (lrow == 0) redmax[wc][wr * 64 + mi * 16 + lkg * 4 + q] = mx;
        }
    __syncthreads();
    float fmv[4][4];
#pragma unroll
    for (int mi = 0; mi < 4; ++mi)
#pragma unroll
        for (int q = 0; q < 4; ++q) {
            int rl = wr * 64 + mi * 16 + lkg * 4 + q;
            float fm = fmaxf(redmax[0][rl], redmax[1][rl]);
            fmv[mi][q] = fm;
            float e = expf(vb[mi][0][q] - fm) + expf(vb[mi][1][q] - fm);
#pragma unroll
            for (int o = 1; o < 16; o <<= 1) e += __shfl_xor(e, o);
            if (lrow == 0) redsum[wc][rl] = e;
        }
    __syncthreads();
#pragma unroll
    for (int mi = 0; mi < 4; ++mi)
#pragma unroll
        for (int q = 0; q < 4; ++q) {
            int rl = wr * 64 + mi * 16 + lkg * 4 + q;
            int m = m0 + rl;
            if (m < M) {
                float ls = logf(redsum[0][rl] + redsum[1][rl]) + fmv[mi][q];
                out[(size_t)m * 64 + wc * 32 + lrow] = vb[mi][0][q] - ls;
                out[(size_t)m * 64 + wc * 32 + 16 + lrow] = vb[mi][1][q] - ls;
            }
        }
}

// ---------------- per-node gate scalars (layer 0 only; layer 1 fused into agg0) ----------
__global__ void k_ab(const uint32_t* __restrict__ hbv, const float* __restrict__ gw,
                     const float* __restrict__ gb, int layer,
                     const float* __restrict__ dinv,
                     float* __restrict__ av, float2* __restrict__ bd, int N) {
    int wid = threadIdx.x >> 6, lane = threadIdx.x & 63;
    int i = blockIdx.x * 4 + wid;
    if (i >= N) return;
    uint32_t u = hbv[(size_t)i * 64 + lane];
    float hx = bflo(u), hy = bfhi(u);
    float2 wi = *(const float2*)&gw[lane * 2];
    float2 wj = *(const float2*)&gw[128 + lane * 2];
    float pa = hx * wi.x + hy * wi.y;
    float pb = hx * wj.x + hy * wj.y;
    for (int o = 1; o < 64; o <<= 1) {
        pa += __shfl_xor(pa, o);
        pb += __shfl_xor(pb, o);
    }
    if (lane == 0) {
        av[i] = pa + gb[layer];
        bd[i] = make_float2(pb, dinv[i]);
    }
}

// ---------------- aggregation ----------------
// wave per node. Phase A: vector weight compute, pack (w_bf16<<16 | c).
// Phase B: 8 edges/iter (2 independent gathers in flight per lane).
// Phase C: cross-group reduce. Phase D: write (lanes 0-15, uint4).
// Phase E (FUSE_AB): compute next layer's av/bd from the output row.
template <bool FUSE_AB, bool RAW_NT>
__global__ __launch_bounds__(256) void k_agg(const uint32_t* __restrict__ hb,
                                             const uint32_t* __restrict__ raw,
                                             const int* __restrict__ rp,
                                             const int* __restrict__ ecol,
                                             const float* __restrict__ av,
                                             const float2* __restrict__ bd,
                                             const float* __restrict__ dinv,
                                             uint32_t* __restrict__ hb_out,
                                             const float* __restrict__ gw_next,
                                             const float* __restrict__ gb_next,
                                             float* __restrict__ av_out,
                                             float2* __restrict__ bd_out, int N) {
    int wid = threadIdx.x >> 6, lane = threadIdx.x & 63;
    int i = blockIdx.x * 4 + wid;
    if (i >= N) return;
    int iu = __builtin_amdgcn_readfirstlane(i);
    int p0 = __builtin_amdgcn_readfirstlane(rp[iu]);
    int p1 = __builtin_amdgcn_readfirstlane(rp[iu + 1]);
    float a_i = av[iu];
    float di = dinv[iu];
    const int lg = lane >> 4;   // edge sub-slot
    const int ll = lane & 15;   // channel quad

    // issue raw-row load EARLY so its latency hides under the gather loop
    uint32_t r0 = 0, r1 = 0, r2 = 0, r3 = 0;
    if (lane < 16) {
        const uint32_t* rpt = raw + (size_t)i * 64 + ll * 4;
        if (RAW_NT) {
            r0 = __builtin_nontemporal_load(rpt + 0);
            r1 = __builtin_nontemporal_load(rpt + 1);
            r2 = __builtin_nontemporal_load(rpt + 2);
            r3 = __builtin_nontemporal_load(rpt + 3);
        } else {
            r0 = rpt[0]; r1 = rpt[1]; r2 = rpt[2]; r3 = rpt[3];
        }
    }

    float acc[8];
#pragma unroll
    for (int j = 0; j < 8; ++j) acc[j] = 0.f;

    for (int b0 = p0; b0 < p1; b0 += 64) {
        int cnt = min(64, p1 - b0);
        // Phase A: vector weight compute for this batch
        uint32_t wcp = 0u;
        if (lane < cnt) {
            int c = __builtin_nontemporal_load(&ecol[b0 + lane]);
            float2 t = bd[c];
            float w = fast_tanh(a_i + t.x) * t.y;
            wcp = (f2bf(w) << 16) | (uint32_t)c;
        }
        // Phase B: 8 edges per iteration (2 gathers in flight per lane)
        int k = 0;
        for (; k + 8 <= cnt; k += 8) {
            uint32_t wx0 = __builtin_amdgcn_ds_bpermute((k + lg) << 2, (int)wcp);
            uint32_t wx1 = __builtin_amdgcn_ds_bpermute((k + 4 + lg) << 2, (int)wcp);
            float w0 = bfhi(wx0);
            float w1 = bfhi(wx1);
            int c0 = (int)(wx0 & 0xffffu);
            int c1 = (int)(wx1 & 0xffffu);
            uint4 u0 = *((const uint4*)(hb + ((size_t)c0 << 6)) + ll);
            uint4 u1 = *((const uint4*)(hb + ((size_t)c1 << 6)) + ll);
            acc[0] = fmaf(w0, bflo(u0.x), acc[0]); acc[1] = fmaf(w0, bfhi(u0.x), acc[1]);
            acc[2] = fmaf(w0, bflo(u0.y), acc[2]); acc[3] = fmaf(w0, bfhi(u0.y), acc[3]);
            acc[4] = fmaf(w0, bflo(u0.z), acc[4]); acc[5] = fmaf(w0, bfhi(u0.z), acc[5]);
            acc[6] = fmaf(w0, bflo(u0.w), acc[6]); acc[7] = fmaf(w0, bfhi(u0.w), acc[7]);
            acc[0] = fmaf(w1, bflo(u1.x), acc[0]); acc[1] = fmaf(w1, bfhi(u1.x), acc[1]);
            acc[2] = fmaf(w1, bflo(u1.y), acc[2]); acc[3] = fmaf(w1, bfhi(u1.y), acc[3]);
            acc[4] = fmaf(w1, bflo(u1.z), acc[4]); acc[5] = fmaf(w1, bfhi(u1.z), acc[5]);
            acc[6] = fmaf(w1, bflo(u1.w), acc[6]); acc[7] = fmaf(w1, bfhi(u1.w), acc[7]);
        }
        for (; k < cnt; k += 4) {
            uint32_t wx = __builtin_amdgcn_ds_bpermute((k + lg) << 2, (int)wcp);
            float w = bfhi(wx);           // 0 for out-of-range slots
            int c = (int)(wx & 0xffffu);
            uint4 u = *((const uint4*)(hb + ((size_t)c << 6)) + ll);
            acc[0] = fmaf(w, bflo(u.x), acc[0]); acc[1] = fmaf(w, bfhi(u.x), acc[1]);
            acc[2] = fmaf(w, bflo(u.y), acc[2]); acc[3] = fmaf(w, bfhi(u.y), acc[3]);
            acc[4] = fmaf(w, bflo(u.z), acc[4]); acc[5] = fmaf(w, bfhi(u.z), acc[5]);
            acc[6] = fmaf(w, bflo(u.w), acc[6]); acc[7] = fmaf(w, bfhi(u.w), acc[7]);
        }
    }
    // Phase C: reduce across the 4 edge sub-slots
#pragma unroll
    for (int j = 0; j < 8; ++j) {
        acc[j] += __shfl_xor(acc[j], 16);
        acc[j] += __shfl_xor(acc[j], 32);
    }
    // Phase D (+E): lanes 0-15 own 8 channels each
    if (lane < 16) {
        float o[8];
        o[0] = EPSF * bflo(r0) + di * acc[0]; o[1] = EPSF * bfhi(r0) + di * acc[1];
        o[2] = EPSF * bflo(r1) + di * acc[2]; o[3] = EPSF * bfhi(r1) + di * acc[3];
        o[4] = EPSF * bflo(r2) + di * acc[4]; o[5] = EPSF * bfhi(r2) + di * acc[5];
        o[6] = EPSF * bflo(r3) + di * acc[6]; o[7] = EPSF * bfhi(r3) + di * acc[7];
        uint4 w4;
        w4.x = pack2(o[0], o[1]); w4.y = pack2(o[2], o[3]);
        w4.z = pack2(o[4], o[5]); w4.w = pack2(o[6], o[7]);
        *((uint4*)(hb_out + (size_t)i * 64) + ll) = w4;
        if (FUSE_AB) {
            float pa = 0.f, pb = 0.f;
#pragma unroll
            for (int j = 0; j < 8; ++j) {
                int ch = ll * 8 + j;
                pa = fmaf(o[j], gw_next[ch], pa);
                pb = fmaf(o[j], gw_next[128 + ch], pb);
            }
#pragma unroll
            for (int off = 1; off < 16; off <<= 1) {
                pa += __shfl_xor(pa, off);
                pb += __shfl_xor(pb, off);
            }
            if (ll == 0) {
                av_out[i] = pa + gb_next[0];
                bd_out[i] = make_float2(pb, di);
            }
        }
    }
}

extern "C" void kernel_launch(void* const* d_in, const int* in_sizes, int n_in,
                              void* d_out, int out_size, void* d_ws, size_t ws_size,
                              hipStream_t stream) {
    const float* x = (const float*)d_in[0];
    const int* ei = (const int*)d_in[1];
    const float* t1w = (const float*)d_in[2];
    const float* t1b = (const float*)d_in[3];
    const float* gw = (const float*)d_in[4];
    const float* gb = (const float*)d_in[5];
    const float* t2w = (const float*)d_in[6];
    const float* t2b = (const float*)d_in[7];
    float* out = (float*)d_out;

    const int INC = 256;
    const int N = in_sizes[0] / INC;
    const int E = in_sizes[1] / 2;
    const int NB = (N + NPB - 1) >> SHB;
    const int nblk = (E + CHUNK - 1) / CHUNK;

    char* ws = (char*)d_ws;
    auto alloc = [&](size_t bytes) {
        char* p = ws;
        ws += (bytes + 255) & ~(size_t)255;
        return p;
    };
    int* hist = (int*)alloc((size_t)NB * nblk * 4);
    int* btot = (int*)alloc((size_t)NB * 4);
    int* bbase = (int*)alloc((size_t)(NB + 1) * 4);
    uint32_t* ebuf = (uint32_t*)alloc((size_t)E * 4);
    int* rp = (int*)alloc((size_t)(N + 1) * 4);
    float* dinv = (float*)alloc((size_t)N * 4);
    int* ecol = (int*)alloc((size_t)E * 4);
    float* av0 = (float*)alloc((size_t)N * 4);
    float* av1 = (float*)alloc((size_t)N * 4);
    float2* bd0 = (float2*)alloc((size_t)N * 8);
    float2* bd1 = (float2*)alloc((size_t)N * 8);
    uint32_t* hb0 = (uint32_t*)alloc((size_t)N * 64 * 4);
    uint32_t* hb1 = (uint32_t*)alloc((size_t)N * 64 * 4);
    uint32_t* hb2 = (uint32_t*)alloc((size_t)N * 64 * 4);

    // ---- CSR build (no global atomics, per-block dtype detect) ----
    k_hist<<<nblk, 256, 0, stream>>>(ei, E, hist, nblk, NB);
    k_scanA<<<NB, 64, 0, stream>>>(hist, nblk, btot);
    k_scanB<<<1, MAXNB, 0, stream>>>(btot, NB, bbase);
    k_binwrite<<<nblk, 256, 0, stream>>>(ei, E, hist, bbase, ebuf, nblk, NB);
    k_csr<<<NB, 256, 0, stream>>>(ebuf, bbase, rp, dinv, ecol, N, E, NB);

    // ---- hb0 = relu(x @ t1_w^T + t1_b) (bf16, MFMA) ----
    k_gemm1<<<(N + 127) / 128, 256, 0, stream>>>(x, t1w, t1b, hb0, N);

    // ---- layer 0 gate scalars ----
    k_ab<<<(N + 3) / 4, 256, 0, stream>>>(hb0, gw + 0 * 256, gb, 0, dinv, av0, bd0, N);
    // ---- layer 0: hb0 -> hb1, fused layer-1 ab ----
    k_agg<true, false><<<(N + 3) / 4, 256, 0, stream>>>(
        hb0, hb0, rp, ecol, av0, bd0, dinv, hb1, gw + 1 * 256, gb + 1, av1, bd1, N);
    // ---- layer 1: hb1 -> hb2 (raw = hb0, nontemporal) ----
    k_agg<false, true><<<(N + 3) / 4, 256, 0, stream>>>(
        hb1, hb0, rp, ecol, av1, bd1, dinv, hb2, nullptr, nullptr, nullptr, nullptr, N);

    // ---- out = log_softmax(hb2 @ t2_w^T + t2_b) (MFMA, fused) ----
    k_gemm2<<<(N + 127) / 128, 256, 0, stream>>>(hb2, t2w, t2b, out, N);
}